// Round 2
// baseline (1161.120 us; speedup 1.0000x reference)
//
#include <hip/hip_runtime.h>
#include <hip/hip_bf16.h>

// AUGRU dynamic RNN: B=1024, T=512, D=128. 64 blocks x 512 thr (8 waves),
// block owns 16 batch rows for all T steps.
// R2 restructure: operand-swapped MFMA (gate^T = GK^T @ in^T) so the C/D
// layout puts col=lane=batch-row, row=quad*4+i=feature-col. h, u' live in
// registers; r*h and h-mirror are contiguous ds_write_b64; OUT is float4.
// Weights = A-frags in regs (96 VGPR). Data [x,h,rh] = B-frags from LDS
// row-major [batch][col] tiles. 2 barriers/step, single-buffered x tile.

#define Bn 1024
#define Tn 512
#define Dn 128

typedef __attribute__((ext_vector_type(8))) short short8;   // 8 bf16 (4 VGPR)
typedef __attribute__((ext_vector_type(4))) short short4v;
typedef __attribute__((ext_vector_type(4))) float f32x4;

#define BS 136   // bf16 LDS row stride in shorts (272 B; 16B-aligned rows)

__device__ __forceinline__ short f2bf(float f) {
    __hip_bfloat16 h = __float2bfloat16(f);   // RNE
    return __builtin_bit_cast(short, h);
}
__device__ __forceinline__ float sigmoidf_(float x) {
    float e = __expf(-x);
    return __builtin_amdgcn_rcpf(1.0f + e);
}
__device__ __forceinline__ float tanhf_(float x) {
    float e = __expf(-2.0f * x);
    return 2.0f * __builtin_amdgcn_rcpf(1.0f + e) - 1.0f;
}
#define MFMA(A, B, C) __builtin_amdgcn_mfma_f32_16x16x32_bf16((A), (B), (C), 0, 0, 0)

__launch_bounds__(512, 2)
__global__ void augru_kernel(const float* __restrict__ X,    // [B,T,D]
                             const float* __restrict__ ATT,  // [B,T,1]
                             const float* __restrict__ GK,   // [256,256]
                             const float* __restrict__ GB,   // [256]
                             const float* __restrict__ CK,   // [256,128]
                             const float* __restrict__ CB,   // [128]
                             const int*   __restrict__ SL,   // [B,1]
                             float* __restrict__ OUT) {      // [B,T,D]
    __shared__ short xb [16 * BS];   // x_t   bf16 [batch][col]
    __shared__ short hb [16 * BS];   // h     bf16 [batch][col]
    __shared__ short rhb[16 * BS];   // r*h   bf16 [batch][col]
    __shared__ float abuf[16];

    const int tid  = threadIdx.x;
    const int wid  = tid >> 6;          // 0..7 : feature block
    const int lane = tid & 63;
    const int lm   = lane & 15;         // batch row within tile (B-frag n / C col)
    const int q    = lane >> 4;         // quad
    const int b0   = blockIdx.x * 16;

    // ---------- weight A-frags: A[m=lane&15][k=q*8+j] = W^T[m][k] = W[k][col] ----
    // wave w owns gate r-cols [16w,16w+16), u-cols [128+16w,..), cand cols [16w,..)
    short8 far[4], fhr[4], fau[4], fhu[4], fcx[4], fcr[4];
#pragma unroll
    for (int ks = 0; ks < 4; ++ks) {
        short8 a0, a1, a2, a3, a4, a5;
#pragma unroll
        for (int j = 0; j < 8; ++j) {
            const int k = ks * 32 + q * 8 + j;
            const int rc = 16 * wid + lm;         // r / cand col
            const int uc = 128 + 16 * wid + lm;   // u col
            a0[j] = f2bf(GK[k * 256 + rc]);           // r, x-part
            a1[j] = f2bf(GK[(128 + k) * 256 + rc]);   // r, h-part
            a2[j] = f2bf(GK[k * 256 + uc]);           // u, x-part
            a3[j] = f2bf(GK[(128 + k) * 256 + uc]);   // u, h-part
            a4[j] = f2bf(CK[k * 128 + rc]);           // cand, x-part
            a5[j] = f2bf(CK[(128 + k) * 128 + rc]);   // cand, rh-part
        }
        far[ks] = a0; fhr[ks] = a1; fau[ks] = a2; fhu[ks] = a3;
        fcx[ks] = a4; fcr[ks] = a5;
    }
    // biases: this lane's 4 feature cols are 16*wid + q*4 + i
    const int cbase = 16 * wid + q * 4;
    f32x4 gbr, gbu, cbv;
#pragma unroll
    for (int i = 0; i < 4; ++i) {
        gbr[i] = GB[cbase + i];
        gbu[i] = GB[128 + cbase + i];
        cbv[i] = CB[cbase + i];
    }
    const int len = SL[b0 + lm];

    // ---------- init ----------
    for (int i = tid; i < 16 * BS; i += 512) hb[i] = 0;
    const int prow = tid >> 5;            // x staging: row 0..15
    const int pcol = (tid & 31) * 4;      // 4 consecutive cols
    {   // stage x and att for t=0
        float4 v = *(const float4*)(X + ((size_t)(b0 + prow) * Tn) * Dn + pcol);
        short4v s; s[0] = f2bf(v.x); s[1] = f2bf(v.y); s[2] = f2bf(v.z); s[3] = f2bf(v.w);
        *(short4v*)&xb[prow * BS + pcol] = s;
        if (tid < 16) abuf[tid] = ATT[(size_t)(b0 + tid) * Tn];
    }
    __syncthreads();

    f32x4 hreg = {0.f, 0.f, 0.f, 0.f};   // h[batch=lm][cbase+i]
    const short* xrow  = &xb[lm * BS + q * 8];
    const short* hrow  = &hb[lm * BS + q * 8];
    const short* rhrow = &rhb[lm * BS + q * 8];
    float* outp = OUT + (size_t)(b0 + lm) * Tn * Dn + cbase;

    // ---------- time loop ----------
    for (int t = 0; t < Tn; ++t) {
        // B-frags: B[k=q*8+j][n=lm] = data[batch=lm][k]
        short8 bx[4], bh[4];
#pragma unroll
        for (int ks = 0; ks < 4; ++ks) {
            bx[ks] = *(const short8*)(xrow + ks * 32);
            bh[ks] = *(const short8*)(hrow + ks * 32);
        }
        const float att_a = abuf[lm];

        // prefetch x/att for t+1
        const int tp = (t + 1 < Tn) ? t + 1 : Tn - 1;
        const float4 xpre = *(const float4*)(X + ((size_t)(b0 + prow) * Tn + tp) * Dn + pcol);
        const float  apre = (tid < 16) ? ATT[(size_t)(b0 + tid) * Tn + tp] : 0.0f;

        // gate MFMA: 4 independent 4-deep chains
        f32x4 rlo = {0.f,0.f,0.f,0.f}, rhi = {0.f,0.f,0.f,0.f};
        f32x4 ulo = {0.f,0.f,0.f,0.f}, uhi = {0.f,0.f,0.f,0.f};
        rlo = MFMA(far[0], bx[0], rlo);  ulo = MFMA(fau[0], bx[0], ulo);
        rhi = MFMA(far[2], bx[2], rhi);  uhi = MFMA(fau[2], bx[2], uhi);
        rlo = MFMA(fhr[0], bh[0], rlo);  ulo = MFMA(fhu[0], bh[0], ulo);
        rhi = MFMA(fhr[2], bh[2], rhi);  uhi = MFMA(fhu[2], bh[2], uhi);
        rlo = MFMA(far[1], bx[1], rlo);  ulo = MFMA(fau[1], bx[1], ulo);
        rhi = MFMA(far[3], bx[3], rhi);  uhi = MFMA(fau[3], bx[3], uhi);
        rlo = MFMA(fhr[1], bh[1], rlo);  ulo = MFMA(fhu[1], bh[1], ulo);
        rhi = MFMA(fhr[3], bh[3], rhi);  uhi = MFMA(fhu[3], bh[3], uhi);
        rlo += rhi; ulo += uhi;

        // activations in registers (lane owns batch lm, cols cbase+i)
        f32x4 up;
        short4v rhs;
#pragma unroll
        for (int i = 0; i < 4; ++i) {
            const float r = sigmoidf_(rlo[i] + gbr[i]);
            const float u = sigmoidf_(ulo[i] + gbu[i]);
            up[i] = (1.0f - att_a) * u;
            rhs[i] = f2bf(r * hreg[i]);
        }
        *(short4v*)&rhb[lm * BS + cbase] = rhs;
        __syncthreads();   // barrier 1: rhb visible; hb/xb reads done

        // cand MFMA: 2 independent 4-deep chains (x B-frags reused from regs)
        short8 brh[4];
#pragma unroll
        for (int ks = 0; ks < 4; ++ks) brh[ks] = *(const short8*)(rhrow + ks * 32);
        f32x4 clo = {0.f,0.f,0.f,0.f}, chi = {0.f,0.f,0.f,0.f};
        clo = MFMA(fcx[0], bx[0],  clo);  chi = MFMA(fcx[2], bx[2],  chi);
        clo = MFMA(fcr[0], brh[0], clo);  chi = MFMA(fcr[2], brh[2], chi);
        clo = MFMA(fcx[1], bx[1],  clo);  chi = MFMA(fcx[3], bx[3],  chi);
        clo = MFMA(fcr[1], brh[1], clo);  chi = MFMA(fcr[3], brh[3], chi);
        clo += chi;

        // h update in registers; float4 OUT store; bf16 h mirror to LDS
        const bool valid = (t < len);
        f32x4 outv;
        short4v hs;
#pragma unroll
        for (int i = 0; i < 4; ++i) {
            const float c  = tanhf_(clo[i] + cbv[i]);
            const float hn = up[i] * hreg[i] + (1.0f - up[i]) * c;
            hreg[i] = valid ? hn : hreg[i];
            outv[i] = valid ? hn : 0.0f;
            hs[i]   = f2bf(hreg[i]);
        }
        *(f32x4*)(outp + (size_t)t * Dn) = outv;
        *(short4v*)&hb[lm * BS + cbase] = hs;

        // stage prefetched x/att (single buffer: all reads completed pre-barrier1)
        {
            short4v s; s[0] = f2bf(xpre.x); s[1] = f2bf(xpre.y);
                       s[2] = f2bf(xpre.z); s[3] = f2bf(xpre.w);
            *(short4v*)&xb[prow * BS + pcol] = s;
            if (tid < 16) abuf[tid] = apre;
        }
        __syncthreads();   // barrier 2: h/x/att for step t+1 visible
    }
}

extern "C" void kernel_launch(void* const* d_in, const int* in_sizes, int n_in,
                              void* d_out, int out_size, void* d_ws, size_t ws_size,
                              hipStream_t stream) {
    (void)in_sizes; (void)n_in; (void)d_ws; (void)ws_size; (void)out_size;
    const float* X   = (const float*)d_in[0];
    const float* ATT = (const float*)d_in[1];
    const float* GK  = (const float*)d_in[2];
    const float* GB  = (const float*)d_in[3];
    const float* CK  = (const float*)d_in[4];
    const float* CB  = (const float*)d_in[5];
    const int*   SL  = (const int*)d_in[6];
    float* OUT = (float*)d_out;

    augru_kernel<<<dim3(Bn / 16), dim3(512), 0, stream>>>(X, ATT, GK, GB, CK, CB, SL, OUT);
}